// Round 6
// baseline (1701.922 us; speedup 1.0000x reference)
//
#include <hip/hip_runtime.h>
#include <math.h>

#define SEQ 2048
#define DIM 1024
#define NBLK 768   // 3 blocks/CU; cap is >=4 (launch_bounds + 32KB LDS) -> all resident, margin 1+

typedef __attribute__((ext_vector_type(8))) _Float16 half8;
typedef __attribute__((ext_vector_type(4))) float f32x4;

__device__ __forceinline__ unsigned short f2h(float f) {
    union { _Float16 h; unsigned short u; } c; c.h = (_Float16)f;
    return c.u;
}
__device__ __forceinline__ float gmask(int k) {
    float t = ((float)k - 1024.0f) * (1.0f / 512.0f);
    return expf(-0.5f * t * t);
}
__device__ __forceinline__ void glds16(const unsigned short* gp, unsigned short* lp) {
    __builtin_amdgcn_global_load_lds((const __attribute__((address_space(1))) void*)gp,
                                     (__attribute__((address_space(3))) void*)lp, 16, 0, 0);
}

// Stage a 128x64 fp16 tile (16 KB) from global (row stride ldK) into lds.
// LDS slot g^(r&7) holds global seg g; 0 bank conflicts with the 16x16
// fragment read pattern below (R0-proven; unchanged).
__device__ __forceinline__ void stage64(const unsigned short* __restrict__ g, int ldK,
                                        unsigned short* lds, int wave, int lane) {
    int row = wave * 32 + (lane >> 3);
    int seg = (lane & 7) ^ (lane >> 3);
    const unsigned short* gp = g + (long)row * ldK + seg * 8;
    unsigned short* lp = lds + wave * 2048;
    glds16(gp, lp);
    glds16(gp + 8 * (long)ldK, lp + 512);
    glds16(gp + 16 * (long)ldK, lp + 1024);
    glds16(gp + 24 * (long)ldK, lp + 1536);
}

enum { EPI_QKV = 0, EPI_EXP = 1, EPI_PV = 2, EPI_OUT = 3 };

// ---- persistent-kernel sync primitives ----
// Grid barrier: device-scope (agent) atomics + threadfence handle cross-XCD
// L2 non-coherence. Monotonic targets (NBLK*(k+1)); counters memset to 0
// on-stream before each launch.
__device__ __forceinline__ void gbar(unsigned* bar, unsigned target) {
    __syncthreads();
    if (threadIdx.x == 0) {
        __threadfence();   // release my block's writes agent-wide
        __hip_atomic_fetch_add(bar, 1u, __ATOMIC_RELEASE, __HIP_MEMORY_SCOPE_AGENT);
        while (__hip_atomic_load(bar, __ATOMIC_ACQUIRE, __HIP_MEMORY_SCOPE_AGENT) < target)
            __builtin_amdgcn_s_sleep(2);
        __threadfence();   // acquire others' writes
    }
    __syncthreads();
}
// Dynamic tile ticket: self-balancing across CUs regardless of block->CU map.
__device__ __forceinline__ int tick(unsigned* t, unsigned* cur) {
    __syncthreads();   // protect *cur reuse across iterations
    if (threadIdx.x == 0)
        *cur = __hip_atomic_fetch_add(t, 1u, __ATOMIC_RELAXED, __HIP_MEMORY_SCOPE_AGENT);
    __syncthreads();
    return (int)*cur;
}

// C = A @ B^T with 16x16x32 fp16 MFMA. A:[M,K], B:[N,K] fp16 row-major.
// Bodies identical to the proven R0 (fused QKV) / R5 (ones-MFMA PV) versions;
// only blockIdx -> (bx,by,bz) args and LDS passed in (shared across stages).
// EPI_QKV: N=3072 packed; writes Q, K (row-major) and V^T [b][d][s] (+bias).
// EPI_EXP: writes fp16 exp(acc*scale*gmask(n)).
// EPI_PV : rowsum via rs=mfma(a,ones,rs) (D-layout puts row lk*4+r sums in
//          exactly the regs of the thread that writes those rows); writes
//          fp16 acc/rowsum.
// EPI_OUT: writes fp32 acc + bias(n).
template <int EPI>
__device__ __forceinline__ void gemm_body(
    unsigned short* As, unsigned short* Bs, int bx, int by, int bz,
    const unsigned short* __restrict__ A, const unsigned short* __restrict__ Bm,
    const float* __restrict__ bias,
    float* __restrict__ Cf, unsigned short* __restrict__ Ch,
    int M, int N, int K, float scale, long sA, long sB, long sC)
{
    const int tid = threadIdx.x;
    const int wave = tid >> 6;
    const int lane = tid & 63;
    const int wm = (wave & 1) * 64;
    const int wn = (wave >> 1) * 64;
    const long m0 = (long)by * 128;
    const long n0 = (long)bx * 128;
    const int lm = lane & 15;
    const int lk = lane >> 4;

    const unsigned short* pA = A + bz * sA + m0 * K;
    const unsigned short* pB = Bm + bz * sB + n0 * K;

    f32x4 acc[4][4];
#pragma unroll
    for (int i = 0; i < 4; ++i)
#pragma unroll
        for (int j = 0; j < 4; ++j) {
            acc[i][j].x = 0.f; acc[i][j].y = 0.f; acc[i][j].z = 0.f; acc[i][j].w = 0.f;
        }
    f32x4 rs[4];
#pragma unroll
    for (int i = 0; i < 4; ++i) { rs[i].x = 0.f; rs[i].y = 0.f; rs[i].z = 0.f; rs[i].w = 0.f; }
    half8 vone;
#pragma unroll
    for (int e = 0; e < 8; ++e) vone[e] = (_Float16)1.0f;

    int aoff[4][2], boff[4][2];
#pragma unroll
    for (int i = 0; i < 4; ++i)
#pragma unroll
        for (int t = 0; t < 2; ++t) {
            int ar = wm + i * 16 + lm;
            aoff[i][t] = ar * 64 + (((4 * t + lk) ^ (ar & 7)) << 3);
            int br = wn + i * 16 + lm;
            boff[i][t] = br * 64 + (((4 * t + lk) ^ (br & 7)) << 3);
        }

    for (int k0 = 0; k0 < K; k0 += 64) {
        stage64(pA + k0, K, As, wave, lane);
        stage64(pB + k0, K, Bs, wave, lane);
        __syncthreads();

#pragma unroll
        for (int t = 0; t < 2; ++t) {
            half8 a[4], b[4];
#pragma unroll
            for (int i = 0; i < 4; ++i) a[i] = *(const half8*)(As + aoff[i][t]);
#pragma unroll
            for (int j = 0; j < 4; ++j) b[j] = *(const half8*)(Bs + boff[j][t]);
#pragma unroll
            for (int i = 0; i < 4; ++i)
#pragma unroll
                for (int j = 0; j < 4; ++j)
                    acc[i][j] = __builtin_amdgcn_mfma_f32_16x16x32_f16(a[i], b[j], acc[i][j], 0, 0, 0);
            if (EPI == EPI_PV) {
#pragma unroll
                for (int i = 0; i < 4; ++i)
                    rs[i] = __builtin_amdgcn_mfma_f32_16x16x32_f16(a[i], vone, rs[i], 0, 0, 0);
            }
        }
        __syncthreads();
    }

    // ---- epilogue. C/D layout: col = lane&15, row = (lane>>4)*4 + r  [m89/m91]
    const long MD = 8388608;  // 4*SEQ*DIM
    float* cF = (EPI == EPI_OUT) ? Cf + bz * sC : (float*)nullptr;
    unsigned short* cH = (EPI != EPI_OUT) ? Ch + bz * sC : (unsigned short*)nullptr;

#pragma unroll
    for (int i = 0; i < 4; ++i) {
        long mrow = m0 + wm + i * 16 + lk * 4;   // rows mrow..mrow+3
        float inv4[4];
        if (EPI == EPI_PV) {
#pragma unroll
            for (int r = 0; r < 4; ++r)
                inv4[r] = 1.0f / rs[i][r];
        }
#pragma unroll
        for (int j = 0; j < 4; ++j) {
            int n = (int)n0 + wn + j * 16 + lm;
            if (EPI == EPI_QKV) {
                int sel = n >> 10;   // block-uniform (n0 multiple of 128)
                int n1 = n & 1023;
                float bs = bias[n];
                if (sel < 2) {
                    unsigned short* dst = cH + (long)sel * MD;
#pragma unroll
                    for (int r = 0; r < 4; ++r)
                        dst[(mrow + r) * (long)DIM + n1] = f2h(acc[i][j][r] + bs);
                } else {
                    long b = mrow >> 11, s = mrow & 2047;
                    long idx = 2 * MD + b * (long)DIM * SEQ + (long)n1 * SEQ + s;
                    unsigned long long pk =
                        (unsigned long long)f2h(acc[i][j].x + bs) |
                        ((unsigned long long)f2h(acc[i][j].y + bs) << 16) |
                        ((unsigned long long)f2h(acc[i][j].z + bs) << 32) |
                        ((unsigned long long)f2h(acc[i][j].w + bs) << 48);
                    *(unsigned long long*)(cH + idx) = pk;
                }
            } else if (EPI == EPI_EXP) {
                float mult = scale * gmask(n);
#pragma unroll
                for (int r = 0; r < 4; ++r)
                    cH[(mrow + r) * (long)N + n] = f2h(expf(acc[i][j][r] * mult));
            } else if (EPI == EPI_PV) {
#pragma unroll
                for (int r = 0; r < 4; ++r)
                    cH[(mrow + r) * (long)N + n] = f2h(acc[i][j][r] * inv4[r]);
            } else {  // EPI_OUT
                float bs = bias[n];
#pragma unroll
                for (int r = 0; r < 4; ++r)
                    cF[(mrow + r) * (long)N + n] = acc[i][j][r] + bs;
            }
        }
    }
}

// ---- ONE persistent kernel: prep -> QKV -> EXP -> PV -> OUT with internal
// grid barriers. Rationale: R0/R5 dark-time ledger shows ~15.6us per launch
// of inter-dispatch gap (78us over 5 launches, 94 over 6) -- larger than any
// remaining per-stage inefficiency. sync[0]=barrier, sync[1..4]=stage tickets.
__global__ __launch_bounds__(256, 4) void mono(
    const float* __restrict__ x,
    const float* __restrict__ Wq, const float* __restrict__ Wk,
    const float* __restrict__ Wv, const float* __restrict__ Wo,
    const float* __restrict__ bq, const float* __restrict__ bk,
    const float* __restrict__ bv, const float* __restrict__ bo,
    float* __restrict__ out,
    unsigned short* __restrict__ xh, unsigned short* __restrict__ Wp,
    float* __restrict__ bqkv, unsigned short* __restrict__ Qh,
    unsigned short* __restrict__ expS, unsigned* __restrict__ sync)
{
    __shared__ unsigned short As[128 * 64];
    __shared__ unsigned short Bs[128 * 64];
    __shared__ unsigned cur;

    const long MD = 8388608;           // 4*SEQ*DIM
    const long WW = (long)DIM * DIM;
    const long SD = (long)SEQ * DIM, SS = (long)SEQ * SEQ;
    unsigned short* VT  = Qh + 2 * MD;
    unsigned short* Woh = Wp + 3 * WW;
    unsigned short* O1  = xh;          // alias: x dead after QKV

    // ---- stage 0: prep (grid-stride; identical math to standalone prep)
    {
        long gid = (long)blockIdx.x * 256 + threadIdx.x;
        if (gid < 3072) {
            int sel = (int)(gid >> 10);
            const float* s = sel == 0 ? bq : sel == 1 ? bk : bv;
            bqkv[gid] = s[gid & 1023];
        }
        const long NX = 8388608 / 4;
        const long NW = 1048576 / 4;
        const long total = NX + 4 * NW;
        for (long i = gid; i < total; i += (long)NBLK * 256) {
            const float* src; unsigned short* dst; long off;
            if (i < NX) { src = x; dst = xh; off = i; }
            else {
                long wi = i - NX;
                int sel = (int)(wi >> 18);
                src = sel == 0 ? Wq : sel == 1 ? Wk : sel == 2 ? Wv : Wo;
                dst = Wp + ((long)sel << 20);
                off = wi & (NW - 1);
            }
            float4 v = ((const float4*)src)[off];
            unsigned long long p = (unsigned long long)f2h(v.x) | ((unsigned long long)f2h(v.y) << 16) |
                                   ((unsigned long long)f2h(v.z) << 32) | ((unsigned long long)f2h(v.w) << 48);
            ((unsigned long long*)dst)[off] = p;
        }
    }
    gbar(sync, NBLK);

    // ---- stage 1: QKV fused  [8192,3072] = xh @ Wqkv^T + bqkv   (1536 tiles)
    for (int t; (t = tick(sync + 1, &cur)) < 1536; )
        gemm_body<EPI_QKV>(As, Bs, t % 24, t / 24, 0,
                           xh, Wp, bqkv, nullptr, Qh,
                           4 * SEQ, 3 * DIM, DIM, 1.0f, 0, 0, 0);
    gbar(sync, 2 * NBLK);

    // ---- stage 2: expS = exp(QK^T/32 * gmask)                   (1024 tiles)
    for (int t; (t = tick(sync + 2, &cur)) < 1024; )
        gemm_body<EPI_EXP>(As, Bs, t % 16, (t / 16) % 16, t / 256,
                           Qh, Qh + MD, nullptr, nullptr, expS,
                           SEQ, SEQ, DIM, 0.03125f, SD, SD, SS);
    gbar(sync, 3 * NBLK);

    // ---- stage 3: O1 = (expS @ V) / rowsum (ones-MFMA rowsum)    (512 tiles)
    for (int t; (t = tick(sync + 3, &cur)) < 512; )
        gemm_body<EPI_PV>(As, Bs, t % 8, (t / 8) % 16, t / 128,
                          expS, VT, nullptr, nullptr, O1,
                          SEQ, DIM, SEQ, 1.0f, SS, SD, SD);
    gbar(sync, 4 * NBLK);

    // ---- stage 4: out = O1 @ Wo^T + bo (fp32)                    (512 tiles)
    for (int t; (t = tick(sync + 4, &cur)) < 512; )
        gemm_body<EPI_OUT>(As, Bs, t % 8, t / 8, 0,
                           O1, Woh, bo, out, nullptr,
                           4 * SEQ, DIM, DIM, 1.0f, 0, 0, 0);
}

extern "C" void kernel_launch(void* const* d_in, const int* in_sizes, int n_in,
                              void* d_out, int out_size, void* d_ws, size_t ws_size,
                              hipStream_t stream)
{
    const float* x  = (const float*)d_in[0];
    const float* Wq = (const float*)d_in[1];
    const float* bq = (const float*)d_in[2];
    const float* Wk = (const float*)d_in[3];
    const float* bk = (const float*)d_in[4];
    const float* Wv = (const float*)d_in[5];
    const float* bv = (const float*)d_in[6];
    const float* Wo = (const float*)d_in[7];
    const float* bo = (const float*)d_in[8];
    float* out = (float*)d_out;

    const long MD = 4L * SEQ * DIM;    // 8M
    const long WW = (long)DIM * DIM;   // 1M
    const long SS = (long)SEQ * SEQ;

    unsigned short* xh   = (unsigned short*)d_ws;           // 16 MB
    unsigned short* Wp   = xh + MD;                         // 8 MB (Wqkv|Wo fp16)
    float* bqkv          = (float*)(Wp + 4 * WW);           // 3072 (+pad)
    unsigned short* Qh   = (unsigned short*)(bqkv + 4096);  // Q|K|VT contiguous 48 MB
    unsigned short* expS = Qh + 3 * MD;                     // 33.5 MB
    unsigned* syncp      = (unsigned*)(expS + 4 * SS);      // 5 counters

    hipMemsetAsync(syncp, 0, 64, stream);
    mono<<<NBLK, dim3(256), 0, stream>>>(
        x, Wq, Wk, Wv, Wo, bq, bk, bv, bo, out,
        xh, Wp, bqkv, Qh, expS, syncp);
}

// Round 7
// 930.235 us; speedup vs baseline: 1.8296x; 1.8296x over previous
//
#include <hip/hip_runtime.h>
#include <math.h>

#define SEQ 2048
#define DIM 1024
#define NBLK 768   // 3 blocks/CU; caps: LDS 32KB->5/CU, launch_bounds 4/CU -> all resident

typedef __attribute__((ext_vector_type(8))) _Float16 half8;
typedef __attribute__((ext_vector_type(4))) float f32x4;

__device__ __forceinline__ unsigned short f2h(float f) {
    union { _Float16 h; unsigned short u; } c; c.h = (_Float16)f;
    return c.u;
}
__device__ __forceinline__ float gmask(int k) {
    float t = ((float)k - 1024.0f) * (1.0f / 512.0f);
    return expf(-0.5f * t * t);
}
__device__ __forceinline__ void glds16(const unsigned short* gp, unsigned short* lp) {
    __builtin_amdgcn_global_load_lds((const __attribute__((address_space(1))) void*)gp,
                                     (__attribute__((address_space(3))) void*)lp, 16, 0, 0);
}

// Stage a 128x64 fp16 tile (16 KB) from global (row stride ldK) into lds.
// LDS slot g^(r&7) holds global seg g; 0 bank conflicts with the 16x16
// fragment read pattern below (R0-proven; unchanged).
__device__ __forceinline__ void stage64(const unsigned short* __restrict__ g, int ldK,
                                        unsigned short* lds, int wave, int lane) {
    int row = wave * 32 + (lane >> 3);
    int seg = (lane & 7) ^ (lane >> 3);
    const unsigned short* gp = g + (long)row * ldK + seg * 8;
    unsigned short* lp = lds + wave * 2048;
    glds16(gp, lp);
    glds16(gp + 8 * (long)ldK, lp + 512);
    glds16(gp + 16 * (long)ldK, lp + 1024);
    glds16(gp + 24 * (long)ldK, lp + 1536);
}

enum { EPI_QKV = 0, EPI_EXP = 1, EPI_PV = 2, EPI_OUT = 3 };

// Grid barrier. R6 post-mortem: the 1.9ms disaster was (a) barrier spin line
// FALSE-SHARED with per-tile ticket RMWs (one 64B line hammered by 768 agents
// across 8 XCDs) and (b) 128-cycle poll period. Fix: NO per-tile atomics
// anywhere (static tile assignment), barrier counter alone on a padded line,
// s_sleep(32) (~2k cycles) poll backoff. Only 4*768 atomics remain total.
__device__ __forceinline__ void gbar(unsigned* bar, unsigned target) {
    __syncthreads();
    if (threadIdx.x == 0) {
        __threadfence();   // release my block's writes agent-wide
        __hip_atomic_fetch_add(bar, 1u, __ATOMIC_RELEASE, __HIP_MEMORY_SCOPE_AGENT);
        while (__hip_atomic_load(bar, __ATOMIC_ACQUIRE, __HIP_MEMORY_SCOPE_AGENT) < target)
            __builtin_amdgcn_s_sleep(32);
        __threadfence();   // acquire others' writes
    }
    __syncthreads();
}

// C = A @ B^T with 16x16x32 fp16 MFMA. A:[M,K], B:[N,K] fp16 row-major.
// Bodies identical to the proven R0 (fused QKV) / R5 (ones-MFMA PV) versions.
// EPI_QKV: N=3072 packed; writes Q, K (row-major) and V^T [b][d][s] (+bias).
// EPI_EXP: writes fp16 exp(acc*scale*gmask(n)).
// EPI_PV : rowsum via rs=mfma(a,ones,rs) (D-layout puts row lk*4+r sums in
//          exactly the regs of the thread that writes those rows); writes
//          fp16 acc/rowsum.
// EPI_OUT: writes fp32 acc + bias(n).
template <int EPI>
__device__ __forceinline__ void gemm_body(
    unsigned short* As, unsigned short* Bs, int bx, int by, int bz,
    const unsigned short* __restrict__ A, const unsigned short* __restrict__ Bm,
    const float* __restrict__ bias,
    float* __restrict__ Cf, unsigned short* __restrict__ Ch,
    int M, int N, int K, float scale, long sA, long sB, long sC)
{
    const int tid = threadIdx.x;
    const int wave = tid >> 6;
    const int lane = tid & 63;
    const int wm = (wave & 1) * 64;
    const int wn = (wave >> 1) * 64;
    const long m0 = (long)by * 128;
    const long n0 = (long)bx * 128;
    const int lm = lane & 15;
    const int lk = lane >> 4;

    const unsigned short* pA = A + bz * sA + m0 * K;
    const unsigned short* pB = Bm + bz * sB + n0 * K;

    f32x4 acc[4][4];
#pragma unroll
    for (int i = 0; i < 4; ++i)
#pragma unroll
        for (int j = 0; j < 4; ++j) {
            acc[i][j].x = 0.f; acc[i][j].y = 0.f; acc[i][j].z = 0.f; acc[i][j].w = 0.f;
        }
    f32x4 rs[4];
#pragma unroll
    for (int i = 0; i < 4; ++i) { rs[i].x = 0.f; rs[i].y = 0.f; rs[i].z = 0.f; rs[i].w = 0.f; }
    half8 vone;
#pragma unroll
    for (int e = 0; e < 8; ++e) vone[e] = (_Float16)1.0f;

    int aoff[4][2], boff[4][2];
#pragma unroll
    for (int i = 0; i < 4; ++i)
#pragma unroll
        for (int t = 0; t < 2; ++t) {
            int ar = wm + i * 16 + lm;
            aoff[i][t] = ar * 64 + (((4 * t + lk) ^ (ar & 7)) << 3);
            int br = wn + i * 16 + lm;
            boff[i][t] = br * 64 + (((4 * t + lk) ^ (br & 7)) << 3);
        }

    for (int k0 = 0; k0 < K; k0 += 64) {
        stage64(pA + k0, K, As, wave, lane);
        stage64(pB + k0, K, Bs, wave, lane);
        __syncthreads();

#pragma unroll
        for (int t = 0; t < 2; ++t) {
            half8 a[4], b[4];
#pragma unroll
            for (int i = 0; i < 4; ++i) a[i] = *(const half8*)(As + aoff[i][t]);
#pragma unroll
            for (int j = 0; j < 4; ++j) b[j] = *(const half8*)(Bs + boff[j][t]);
#pragma unroll
            for (int i = 0; i < 4; ++i)
#pragma unroll
                for (int j = 0; j < 4; ++j)
                    acc[i][j] = __builtin_amdgcn_mfma_f32_16x16x32_f16(a[i], b[j], acc[i][j], 0, 0, 0);
            if (EPI == EPI_PV) {
#pragma unroll
                for (int i = 0; i < 4; ++i)
                    rs[i] = __builtin_amdgcn_mfma_f32_16x16x32_f16(a[i], vone, rs[i], 0, 0, 0);
            }
        }
        __syncthreads();
    }

    // ---- epilogue. C/D layout: col = lane&15, row = (lane>>4)*4 + r  [m89/m91]
    const long MD = 8388608;  // 4*SEQ*DIM
    float* cF = (EPI == EPI_OUT) ? Cf + bz * sC : (float*)nullptr;
    unsigned short* cH = (EPI != EPI_OUT) ? Ch + bz * sC : (unsigned short*)nullptr;

#pragma unroll
    for (int i = 0; i < 4; ++i) {
        long mrow = m0 + wm + i * 16 + lk * 4;   // rows mrow..mrow+3
        float inv4[4];
        if (EPI == EPI_PV) {
#pragma unroll
            for (int r = 0; r < 4; ++r)
                inv4[r] = 1.0f / rs[i][r];
        }
#pragma unroll
        for (int j = 0; j < 4; ++j) {
            int n = (int)n0 + wn + j * 16 + lm;
            if (EPI == EPI_QKV) {
                int sel = n >> 10;   // block-uniform (n0 multiple of 128)
                int n1 = n & 1023;
                float bs = bias[n];
                if (sel < 2) {
                    unsigned short* dst = cH + (long)sel * MD;
#pragma unroll
                    for (int r = 0; r < 4; ++r)
                        dst[(mrow + r) * (long)DIM + n1] = f2h(acc[i][j][r] + bs);
                } else {
                    long b = mrow >> 11, s = mrow & 2047;
                    long idx = 2 * MD + b * (long)DIM * SEQ + (long)n1 * SEQ + s;
                    unsigned long long pk =
                        (unsigned long long)f2h(acc[i][j].x + bs) |
                        ((unsigned long long)f2h(acc[i][j].y + bs) << 16) |
                        ((unsigned long long)f2h(acc[i][j].z + bs) << 32) |
                        ((unsigned long long)f2h(acc[i][j].w + bs) << 48);
                    *(unsigned long long*)(cH + idx) = pk;
                }
            } else if (EPI == EPI_EXP) {
                float mult = scale * gmask(n);
#pragma unroll
                for (int r = 0; r < 4; ++r)
                    cH[(mrow + r) * (long)N + n] = f2h(expf(acc[i][j][r] * mult));
            } else if (EPI == EPI_PV) {
#pragma unroll
                for (int r = 0; r < 4; ++r)
                    cH[(mrow + r) * (long)N + n] = f2h(acc[i][j][r] * inv4[r]);
            } else {  // EPI_OUT
                float bs = bias[n];
#pragma unroll
                for (int r = 0; r < 4; ++r)
                    cF[(mrow + r) * (long)N + n] = acc[i][j][r] + bs;
            }
        }
    }
}

// ---- ONE persistent kernel: prep -> QKV -> EXP -> PV -> OUT with internal
// grid barriers. Ledger (R0/R5): ~15.6us inter-dispatch gap per launch; one
// launch refunds ~78-94us. Static per-block tile assignment (t = bid + k*NBLK)
// -- zero atomics inside stages; 4 barriers total.
__global__ __launch_bounds__(256, 4) void mono(
    const float* __restrict__ x,
    const float* __restrict__ Wq, const float* __restrict__ Wk,
    const float* __restrict__ Wv, const float* __restrict__ Wo,
    const float* __restrict__ bq, const float* __restrict__ bk,
    const float* __restrict__ bv, const float* __restrict__ bo,
    float* __restrict__ out,
    unsigned short* __restrict__ xh, unsigned short* __restrict__ Wp,
    float* __restrict__ bqkv, unsigned short* __restrict__ Qh,
    unsigned short* __restrict__ expS, unsigned* __restrict__ sync)
{
    __shared__ unsigned short As[128 * 64];
    __shared__ unsigned short Bs[128 * 64];

    const long MD = 8388608;           // 4*SEQ*DIM
    const long WW = (long)DIM * DIM;
    const long SD = (long)SEQ * DIM, SS = (long)SEQ * SEQ;
    unsigned short* VT  = Qh + 2 * MD;
    unsigned short* Woh = Wp + 3 * WW;
    unsigned short* O1  = xh;          // alias: x dead after QKV
    const int bid = blockIdx.x;

    // ---- stage 0: prep (grid-stride; identical math to standalone prep)
    {
        long gid = (long)bid * 256 + threadIdx.x;
        if (gid < 3072) {
            int sel = (int)(gid >> 10);
            const float* s = sel == 0 ? bq : sel == 1 ? bk : bv;
            bqkv[gid] = s[gid & 1023];
        }
        const long NX = 8388608 / 4;
        const long NW = 1048576 / 4;
        const long total = NX + 4 * NW;
        for (long i = gid; i < total; i += (long)NBLK * 256) {
            const float* src; unsigned short* dst; long off;
            if (i < NX) { src = x; dst = xh; off = i; }
            else {
                long wi = i - NX;
                int sel = (int)(wi >> 18);
                src = sel == 0 ? Wq : sel == 1 ? Wk : sel == 2 ? Wv : Wo;
                dst = Wp + ((long)sel << 20);
                off = wi & (NW - 1);
            }
            float4 v = ((const float4*)src)[off];
            unsigned long long p = (unsigned long long)f2h(v.x) | ((unsigned long long)f2h(v.y) << 16) |
                                   ((unsigned long long)f2h(v.z) << 32) | ((unsigned long long)f2h(v.w) << 48);
            ((unsigned long long*)dst)[off] = p;
        }
    }
    gbar(sync, NBLK);

    // ---- stage 1: QKV fused  [8192,3072] = xh @ Wqkv^T + bqkv   (1536 tiles)
    for (int t = bid; t < 1536; t += NBLK)
        gemm_body<EPI_QKV>(As, Bs, t % 24, t / 24, 0,
                           xh, Wp, bqkv, nullptr, Qh,
                           4 * SEQ, 3 * DIM, DIM, 1.0f, 0, 0, 0);
    gbar(sync, 2 * NBLK);

    // ---- stage 2: expS = exp(QK^T/32 * gmask)                   (1024 tiles)
    for (int t = bid; t < 1024; t += NBLK)
        gemm_body<EPI_EXP>(As, Bs, t % 16, (t / 16) % 16, t / 256,
                           Qh, Qh + MD, nullptr, nullptr, expS,
                           SEQ, SEQ, DIM, 0.03125f, SD, SD, SS);
    gbar(sync, 3 * NBLK);

    // ---- stage 3: O1 = (expS @ V) / rowsum (ones-MFMA rowsum)    (512 tiles)
    for (int t = bid; t < 512; t += NBLK)
        gemm_body<EPI_PV>(As, Bs, t % 8, (t / 8) % 16, t / 128,
                          expS, VT, nullptr, nullptr, O1,
                          SEQ, DIM, SEQ, 1.0f, SS, SD, SD);
    gbar(sync, 4 * NBLK);

    // ---- stage 4: out = O1 @ Wo^T + bo (fp32)                    (512 tiles)
    for (int t = bid; t < 512; t += NBLK)
        gemm_body<EPI_OUT>(As, Bs, t % 8, t / 8, 0,
                           O1, Woh, bo, out, nullptr,
                           4 * SEQ, DIM, DIM, 1.0f, 0, 0, 0);
}

extern "C" void kernel_launch(void* const* d_in, const int* in_sizes, int n_in,
                              void* d_out, int out_size, void* d_ws, size_t ws_size,
                              hipStream_t stream)
{
    const float* x  = (const float*)d_in[0];
    const float* Wq = (const float*)d_in[1];
    const float* bq = (const float*)d_in[2];
    const float* Wk = (const float*)d_in[3];
    const float* bk = (const float*)d_in[4];
    const float* Wv = (const float*)d_in[5];
    const float* bv = (const float*)d_in[6];
    const float* Wo = (const float*)d_in[7];
    const float* bo = (const float*)d_in[8];
    float* out = (float*)d_out;

    const long MD = 4L * SEQ * DIM;    // 8M
    const long WW = (long)DIM * DIM;   // 1M
    const long SS = (long)SEQ * SEQ;

    unsigned short* xh   = (unsigned short*)d_ws;           // 16 MB
    unsigned short* Wp   = xh + MD;                         // 8 MB (Wqkv|Wo fp16)
    float* bqkv          = (float*)(Wp + 4 * WW);           // 3072 (+pad)
    unsigned short* Qh   = (unsigned short*)(bqkv + 4096);  // Q|K|VT contiguous 48 MB
    unsigned short* expS = Qh + 3 * MD;                     // 33.5 MB
    unsigned* syncp      = (unsigned*)(expS + 4 * SS);      // barrier, padded line

    hipMemsetAsync(syncp, 0, 128, stream);
    mono<<<NBLK, dim3(256), 0, stream>>>(
        x, Wq, Wk, Wv, Wo, bq, bk, bv, bo, out,
        xh, Wp, bqkv, Qh, expS, syncp);
}

// Round 8
// 736.078 us; speedup vs baseline: 2.3121x; 1.2638x over previous
//
#include <hip/hip_runtime.h>
#include <math.h>

#define SEQ 2048
#define DIM 1024
#define NBLK 768   // 3 blocks/CU; caps: LDS 32KB->5/CU, launch_bounds 4/CU -> all resident

typedef __attribute__((ext_vector_type(8))) _Float16 half8;
typedef __attribute__((ext_vector_type(4))) float f32x4;

__device__ __forceinline__ unsigned short f2h(float f) {
    union { _Float16 h; unsigned short u; } c; c.h = (_Float16)f;
    return c.u;
}
__device__ __forceinline__ float gmask(int k) {
    float t = ((float)k - 1024.0f) * (1.0f / 512.0f);
    return expf(-0.5f * t * t);
}
__device__ __forceinline__ void glds16(const unsigned short* gp, unsigned short* lp) {
    __builtin_amdgcn_global_load_lds((const __attribute__((address_space(1))) void*)gp,
                                     (__attribute__((address_space(3))) void*)lp, 16, 0, 0);
}

// Stage a 128x64 fp16 tile (16 KB) from global (row stride ldK) into lds.
// LDS slot g^(r&7) holds global seg g; 0 bank conflicts with the 16x16
// fragment read pattern below (R0-proven; unchanged).
__device__ __forceinline__ void stage64(const unsigned short* __restrict__ g, int ldK,
                                        unsigned short* lds, int wave, int lane) {
    int row = wave * 32 + (lane >> 3);
    int seg = (lane & 7) ^ (lane >> 3);
    const unsigned short* gp = g + (long)row * ldK + seg * 8;
    unsigned short* lp = lds + wave * 2048;
    glds16(gp, lp);
    glds16(gp + 8 * (long)ldK, lp + 512);
    glds16(gp + 16 * (long)ldK, lp + 1024);
    glds16(gp + 24 * (long)ldK, lp + 1536);
}

enum { EPI_QKV = 0, EPI_EXP = 1, EPI_PV = 2, EPI_OUT = 3 };

// Grid barrier -- third iteration. Ledger of poisons removed:
//  R6: per-tile ticket RMWs false-shared with the spin line -> 1.9ms.
//  R7: ACQUIRE in the poll loop -> agent-scope acquire load emits an L2
//      invalidate (cross-XCD coherence) EVERY ~2k-cycle poll x 768 spinners
//      -> working blocks' L2 continuously invalidated -> FETCH +170MB,
//      everything HBM-latency-bound (MfmaUtil 6.8%, 930us).
//  R8 fix: poll with RELAXED (agent-scope relaxed load reads the coherence
//  point WITHOUT invalidating caches); take the acquire ONCE via the
//  __threadfence() after the loop exits. 4 invalidates/block total, at
//  stage boundaries where they are semantically required anyway.
__device__ __forceinline__ void gbar(unsigned* bar, unsigned target) {
    __syncthreads();
    if (threadIdx.x == 0) {
        __threadfence();   // release my block's writes agent-wide
        __hip_atomic_fetch_add(bar, 1u, __ATOMIC_RELEASE, __HIP_MEMORY_SCOPE_AGENT);
        while (__hip_atomic_load(bar, __ATOMIC_RELAXED, __HIP_MEMORY_SCOPE_AGENT) < target)
            __builtin_amdgcn_s_sleep(32);
        __threadfence();   // single acquire: invalidate once, after arrival
    }
    __syncthreads();
}

// C = A @ B^T with 16x16x32 fp16 MFMA. A:[M,K], B:[N,K] fp16 row-major.
// Bodies identical to the proven R0 (fused QKV) / R5 (ones-MFMA PV) versions.
// EPI_QKV: N=3072 packed; writes Q, K (row-major) and V^T [b][d][s] (+bias).
// EPI_EXP: writes fp16 exp(acc*scale*gmask(n)).
// EPI_PV : rowsum via rs=mfma(a,ones,rs) (D-layout puts row lk*4+r sums in
//          exactly the regs of the thread that writes those rows); writes
//          fp16 acc/rowsum.
// EPI_OUT: writes fp32 acc + bias(n).
template <int EPI>
__device__ __forceinline__ void gemm_body(
    unsigned short* As, unsigned short* Bs, int bx, int by, int bz,
    const unsigned short* __restrict__ A, const unsigned short* __restrict__ Bm,
    const float* __restrict__ bias,
    float* __restrict__ Cf, unsigned short* __restrict__ Ch,
    int M, int N, int K, float scale, long sA, long sB, long sC)
{
    const int tid = threadIdx.x;
    const int wave = tid >> 6;
    const int lane = tid & 63;
    const int wm = (wave & 1) * 64;
    const int wn = (wave >> 1) * 64;
    const long m0 = (long)by * 128;
    const long n0 = (long)bx * 128;
    const int lm = lane & 15;
    const int lk = lane >> 4;

    const unsigned short* pA = A + bz * sA + m0 * K;
    const unsigned short* pB = Bm + bz * sB + n0 * K;

    f32x4 acc[4][4];
#pragma unroll
    for (int i = 0; i < 4; ++i)
#pragma unroll
        for (int j = 0; j < 4; ++j) {
            acc[i][j].x = 0.f; acc[i][j].y = 0.f; acc[i][j].z = 0.f; acc[i][j].w = 0.f;
        }
    f32x4 rs[4];
#pragma unroll
    for (int i = 0; i < 4; ++i) { rs[i].x = 0.f; rs[i].y = 0.f; rs[i].z = 0.f; rs[i].w = 0.f; }
    half8 vone;
#pragma unroll
    for (int e = 0; e < 8; ++e) vone[e] = (_Float16)1.0f;

    int aoff[4][2], boff[4][2];
#pragma unroll
    for (int i = 0; i < 4; ++i)
#pragma unroll
        for (int t = 0; t < 2; ++t) {
            int ar = wm + i * 16 + lm;
            aoff[i][t] = ar * 64 + (((4 * t + lk) ^ (ar & 7)) << 3);
            int br = wn + i * 16 + lm;
            boff[i][t] = br * 64 + (((4 * t + lk) ^ (br & 7)) << 3);
        }

    for (int k0 = 0; k0 < K; k0 += 64) {
        stage64(pA + k0, K, As, wave, lane);
        stage64(pB + k0, K, Bs, wave, lane);
        __syncthreads();

#pragma unroll
        for (int t = 0; t < 2; ++t) {
            half8 a[4], b[4];
#pragma unroll
            for (int i = 0; i < 4; ++i) a[i] = *(const half8*)(As + aoff[i][t]);
#pragma unroll
            for (int j = 0; j < 4; ++j) b[j] = *(const half8*)(Bs + boff[j][t]);
#pragma unroll
            for (int i = 0; i < 4; ++i)
#pragma unroll
                for (int j = 0; j < 4; ++j)
                    acc[i][j] = __builtin_amdgcn_mfma_f32_16x16x32_f16(a[i], b[j], acc[i][j], 0, 0, 0);
            if (EPI == EPI_PV) {
#pragma unroll
                for (int i = 0; i < 4; ++i)
                    rs[i] = __builtin_amdgcn_mfma_f32_16x16x32_f16(a[i], vone, rs[i], 0, 0, 0);
            }
        }
        __syncthreads();
    }

    // ---- epilogue. C/D layout: col = lane&15, row = (lane>>4)*4 + r  [m89/m91]
    const long MD = 8388608;  // 4*SEQ*DIM
    float* cF = (EPI == EPI_OUT) ? Cf + bz * sC : (float*)nullptr;
    unsigned short* cH = (EPI != EPI_OUT) ? Ch + bz * sC : (unsigned short*)nullptr;

#pragma unroll
    for (int i = 0; i < 4; ++i) {
        long mrow = m0 + wm + i * 16 + lk * 4;   // rows mrow..mrow+3
        float inv4[4];
        if (EPI == EPI_PV) {
#pragma unroll
            for (int r = 0; r < 4; ++r)
                inv4[r] = 1.0f / rs[i][r];
        }
#pragma unroll
        for (int j = 0; j < 4; ++j) {
            int n = (int)n0 + wn + j * 16 + lm;
            if (EPI == EPI_QKV) {
                int sel = n >> 10;   // block-uniform (n0 multiple of 128)
                int n1 = n & 1023;
                float bs = bias[n];
                if (sel < 2) {
                    unsigned short* dst = cH + (long)sel * MD;
#pragma unroll
                    for (int r = 0; r < 4; ++r)
                        dst[(mrow + r) * (long)DIM + n1] = f2h(acc[i][j][r] + bs);
                } else {
                    long b = mrow >> 11, s = mrow & 2047;
                    long idx = 2 * MD + b * (long)DIM * SEQ + (long)n1 * SEQ + s;
                    unsigned long long pk =
                        (unsigned long long)f2h(acc[i][j].x + bs) |
                        ((unsigned long long)f2h(acc[i][j].y + bs) << 16) |
                        ((unsigned long long)f2h(acc[i][j].z + bs) << 32) |
                        ((unsigned long long)f2h(acc[i][j].w + bs) << 48);
                    *(unsigned long long*)(cH + idx) = pk;
                }
            } else if (EPI == EPI_EXP) {
                float mult = scale * gmask(n);
#pragma unroll
                for (int r = 0; r < 4; ++r)
                    cH[(mrow + r) * (long)N + n] = f2h(expf(acc[i][j][r] * mult));
            } else if (EPI == EPI_PV) {
#pragma unroll
                for (int r = 0; r < 4; ++r)
                    cH[(mrow + r) * (long)N + n] = f2h(acc[i][j][r] * inv4[r]);
            } else {  // EPI_OUT
                float bs = bias[n];
#pragma unroll
                for (int r = 0; r < 4; ++r)
                    cF[(mrow + r) * (long)N + n] = acc[i][j][r] + bs;
            }
        }
    }
}

// ---- ONE persistent kernel: prep -> QKV -> EXP -> PV -> OUT with internal
// grid barriers. Ledger (R0/R5): ~15.6us inter-dispatch gap per launch; one
// launch refunds ~78-94us. Static per-block tile assignment (t = bid + k*NBLK)
// -- zero atomics inside stages; 4 barriers total.
__global__ __launch_bounds__(256, 4) void mono(
    const float* __restrict__ x,
    const float* __restrict__ Wq, const float* __restrict__ Wk,
    const float* __restrict__ Wv, const float* __restrict__ Wo,
    const float* __restrict__ bq, const float* __restrict__ bk,
    const float* __restrict__ bv, const float* __restrict__ bo,
    float* __restrict__ out,
    unsigned short* __restrict__ xh, unsigned short* __restrict__ Wp,
    float* __restrict__ bqkv, unsigned short* __restrict__ Qh,
    unsigned short* __restrict__ expS, unsigned* __restrict__ sync)
{
    __shared__ unsigned short As[128 * 64];
    __shared__ unsigned short Bs[128 * 64];

    const long MD = 8388608;           // 4*SEQ*DIM
    const long WW = (long)DIM * DIM;
    const long SD = (long)SEQ * DIM, SS = (long)SEQ * SEQ;
    unsigned short* VT  = Qh + 2 * MD;
    unsigned short* Woh = Wp + 3 * WW;
    unsigned short* O1  = xh;          // alias: x dead after QKV
    const int bid = blockIdx.x;

    // ---- stage 0: prep (grid-stride; identical math to standalone prep)
    {
        long gid = (long)bid * 256 + threadIdx.x;
        if (gid < 3072) {
            int sel = (int)(gid >> 10);
            const float* s = sel == 0 ? bq : sel == 1 ? bk : bv;
            bqkv[gid] = s[gid & 1023];
        }
        const long NX = 8388608 / 4;
        const long NW = 1048576 / 4;
        const long total = NX + 4 * NW;
        for (long i = gid; i < total; i += (long)NBLK * 256) {
            const float* src; unsigned short* dst; long off;
            if (i < NX) { src = x; dst = xh; off = i; }
            else {
                long wi = i - NX;
                int sel = (int)(wi >> 18);
                src = sel == 0 ? Wq : sel == 1 ? Wk : sel == 2 ? Wv : Wo;
                dst = Wp + ((long)sel << 20);
                off = wi & (NW - 1);
            }
            float4 v = ((const float4*)src)[off];
            unsigned long long p = (unsigned long long)f2h(v.x) | ((unsigned long long)f2h(v.y) << 16) |
                                   ((unsigned long long)f2h(v.z) << 32) | ((unsigned long long)f2h(v.w) << 48);
            ((unsigned long long*)dst)[off] = p;
        }
    }
    gbar(sync, NBLK);

    // ---- stage 1: QKV fused  [8192,3072] = xh @ Wqkv^T + bqkv   (1536 tiles)
    for (int t = bid; t < 1536; t += NBLK)
        gemm_body<EPI_QKV>(As, Bs, t % 24, t / 24, 0,
                           xh, Wp, bqkv, nullptr, Qh,
                           4 * SEQ, 3 * DIM, DIM, 1.0f, 0, 0, 0);
    gbar(sync, 2 * NBLK);

    // ---- stage 2: expS = exp(QK^T/32 * gmask)                   (1024 tiles)
    for (int t = bid; t < 1024; t += NBLK)
        gemm_body<EPI_EXP>(As, Bs, t % 16, (t / 16) % 16, t / 256,
                           Qh, Qh + MD, nullptr, nullptr, expS,
                           SEQ, SEQ, DIM, 0.03125f, SD, SD, SS);
    gbar(sync, 3 * NBLK);

    // ---- stage 3: O1 = (expS @ V) / rowsum (ones-MFMA rowsum)    (512 tiles)
    for (int t = bid; t < 512; t += NBLK)
        gemm_body<EPI_PV>(As, Bs, t % 8, (t / 8) % 16, t / 128,
                          expS, VT, nullptr, nullptr, O1,
                          SEQ, DIM, SEQ, 1.0f, SS, SD, SD);
    gbar(sync, 4 * NBLK);

    // ---- stage 4: out = O1 @ Wo^T + bo (fp32)                    (512 tiles)
    for (int t = bid; t < 512; t += NBLK)
        gemm_body<EPI_OUT>(As, Bs, t % 8, t / 8, 0,
                           O1, Woh, bo, out, nullptr,
                           4 * SEQ, DIM, DIM, 1.0f, 0, 0, 0);
}

extern "C" void kernel_launch(void* const* d_in, const int* in_sizes, int n_in,
                              void* d_out, int out_size, void* d_ws, size_t ws_size,
                              hipStream_t stream)
{
    const float* x  = (const float*)d_in[0];
    const float* Wq = (const float*)d_in[1];
    const float* bq = (const float*)d_in[2];
    const float* Wk = (const float*)d_in[3];
    const float* bk = (const float*)d_in[4];
    const float* Wv = (const float*)d_in[5];
    const float* bv = (const float*)d_in[6];
    const float* Wo = (const float*)d_in[7];
    const float* bo = (const float*)d_in[8];
    float* out = (float*)d_out;

    const long MD = 4L * SEQ * DIM;    // 8M
    const long WW = (long)DIM * DIM;   // 1M
    const long SS = (long)SEQ * SEQ;

    unsigned short* xh   = (unsigned short*)d_ws;           // 16 MB
    unsigned short* Wp   = xh + MD;                         // 8 MB (Wqkv|Wo fp16)
    float* bqkv          = (float*)(Wp + 4 * WW);           // 3072 (+pad)
    unsigned short* Qh   = (unsigned short*)(bqkv + 4096);  // Q|K|VT contiguous 48 MB
    unsigned short* expS = Qh + 3 * MD;                     // 33.5 MB
    unsigned* syncp      = (unsigned*)(expS + 4 * SS);      // barrier, padded line

    hipMemsetAsync(syncp, 0, 128, stream);
    mono<<<NBLK, dim3(256), 0, stream>>>(
        x, Wq, Wk, Wv, Wo, bq, bk, bv, bo, out,
        xh, Wp, bqkv, Qh, expS, syncp);
}